// Round 3
// baseline (16114.693 us; speedup 1.0000x reference)
//
#include <hip/hip_runtime.h>
#include <math.h>

#define N_NODES 65536
#define N_EDGES 524288
#define CH 256

#define FMA4(A4, S, W4) \
  A4.x = fmaf((S), (W4).x, A4.x); A4.y = fmaf((S), (W4).y, A4.y); \
  A4.z = fmaf((S), (W4).z, A4.z); A4.w = fmaf((S), (W4).w, A4.w)

// ---------------------------------------------------------------------------
// Generic tiled fp32 GEMM: C[M,N] = A[M,K] @ B + bias (+relu)
// BT=false: B is [K,N] row-major.  BT=true: B is [N,K] row-major (C = A@B^T).
// 128x128 tile, 256 threads, 8x8 per thread, K-chunks of 8.
// __launch_bounds__(256,4): 8.4KB LDS allows many blocks/CU; cap VGPR at 128
// (needs ~110 live incl. 64 acc) so the accumulators stay in registers.
// ---------------------------------------------------------------------------
template <bool BT, bool RELU>
__global__ __launch_bounds__(256, 4) void gemm_kernel(
    const float* __restrict__ A, const float* __restrict__ B,
    const float* __restrict__ bias, float* __restrict__ Cmat,
    int M, int Nn, int K)
{
  __shared__ float As[8][132];
  __shared__ float Bs[8][132];
  const int tid = threadIdx.x;
  const int bm = blockIdx.y * 128;
  const int bn = blockIdx.x * 128;
  const int tm = (tid >> 4) << 3;
  const int tn = (tid & 15) << 3;
  float acc[8][8];
#pragma unroll
  for (int i = 0; i < 8; ++i)
#pragma unroll
    for (int j = 0; j < 8; ++j) acc[i][j] = 0.f;

  const int nk = (K + 7) >> 3;
  const bool k4 = (K & 3) == 0;
  for (int kc = 0; kc < nk; ++kc) {
    const int k0 = kc << 3;
    {  // stage A: As[k][m] = A[bm+m][k0+k]
      const int r = tid >> 1;
      const int kk = (tid & 1) << 2;
      const int gm = bm + r;
      float va[4] = {0.f, 0.f, 0.f, 0.f};
      if (gm < M) {
        const size_t base = (size_t)gm * K + k0 + kk;
        if (k4 && (k0 + kk + 4 <= K)) {
          const float4 v = *(const float4*)(A + base);
          va[0] = v.x; va[1] = v.y; va[2] = v.z; va[3] = v.w;
        } else {
#pragma unroll
          for (int j = 0; j < 4; ++j)
            if (k0 + kk + j < K) va[j] = A[base + j];
        }
      }
      As[kk + 0][r] = va[0]; As[kk + 1][r] = va[1];
      As[kk + 2][r] = va[2]; As[kk + 3][r] = va[3];
    }
    if (!BT) {
      const int r = tid >> 5;
      const int cb = (tid & 31) << 2;
      float4 v = make_float4(0.f, 0.f, 0.f, 0.f);
      if (k0 + r < K) v = *(const float4*)(B + (size_t)(k0 + r) * Nn + bn + cb);
      *(float4*)&Bs[r][cb] = v;
    } else {
      const int r = tid >> 1;
      const int kk = (tid & 1) << 2;
      float vb[4] = {0.f, 0.f, 0.f, 0.f};
      if (bn + r < Nn) {
        const size_t base = (size_t)(bn + r) * K + k0 + kk;
        if (k4 && (k0 + kk + 4 <= K)) {
          const float4 v = *(const float4*)(B + base);
          vb[0] = v.x; vb[1] = v.y; vb[2] = v.z; vb[3] = v.w;
        } else {
#pragma unroll
          for (int j = 0; j < 4; ++j)
            if (k0 + kk + j < K) vb[j] = B[base + j];
        }
      }
      Bs[kk + 0][r] = vb[0]; Bs[kk + 1][r] = vb[1];
      Bs[kk + 2][r] = vb[2]; Bs[kk + 3][r] = vb[3];
    }
    __syncthreads();
#pragma unroll
    for (int k = 0; k < 8; ++k) {
      const float4 a0 = *(const float4*)&As[k][tm];
      const float4 a1 = *(const float4*)&As[k][tm + 4];
      const float4 b0 = *(const float4*)&Bs[k][tn];
      const float4 b1 = *(const float4*)&Bs[k][tn + 4];
      const float av[8] = {a0.x, a0.y, a0.z, a0.w, a1.x, a1.y, a1.z, a1.w};
      const float bv[8] = {b0.x, b0.y, b0.z, b0.w, b1.x, b1.y, b1.z, b1.w};
#pragma unroll
      for (int i = 0; i < 8; ++i)
#pragma unroll
        for (int j = 0; j < 8; ++j)
          acc[i][j] = fmaf(av[i], bv[j], acc[i][j]);
    }
    __syncthreads();
  }
#pragma unroll
  for (int i = 0; i < 8; ++i) {
    const int gm = bm + tm + i;
    if (gm >= M) continue;
    float* crow = Cmat + (size_t)gm * Nn + bn + tn;
#pragma unroll
    for (int j = 0; j < 8; ++j) {
      const int gn = bn + tn + j;
      if (gn >= Nn) continue;
      float v = acc[i][j] + (bias ? bias[gn] : 0.f);
      if (RELU) v = fmaxf(v, 0.f);
      crow[j] = v;
    }
  }
}

// ---------------------------------------------------------------------------
// CSR build: histogram of dst -> exclusive scan -> scatter edge ids.
// ---------------------------------------------------------------------------
__global__ __launch_bounds__(256) void hist_kernel(
    const int* __restrict__ dst, int* __restrict__ deg)
{
  const int e = blockIdx.x * 256 + threadIdx.x;
  atomicAdd(&deg[dst[e]], 1);
}

__global__ __launch_bounds__(256) void scan_kernel(
    const int* __restrict__ deg, int* __restrict__ row_ptr,
    int* __restrict__ fill)
{
  __shared__ int part[256];
  const int t = threadIdx.x;
  const int base = t << 8;
  int s = 0;
  for (int j = 0; j < 256; ++j) s += deg[base + j];
  part[t] = s;
  __syncthreads();
  for (int off = 1; off < 256; off <<= 1) {
    int v = (t >= off) ? part[t - off] : 0;
    __syncthreads();
    part[t] += v;
    __syncthreads();
  }
  int run = (t == 0) ? 0 : part[t - 1];
  for (int j = 0; j < 256; ++j) {
    row_ptr[base + j] = run;
    fill[base + j] = run;
    run += deg[base + j];
  }
  if (t == 255) row_ptr[65536] = run;
}

__global__ __launch_bounds__(256) void scatter_kernel(
    const int* __restrict__ dst, int* __restrict__ fill,
    int* __restrict__ eid)
{
  const int e = blockIdx.x * 256 + threadIdx.x;
  const int pos = atomicAdd(&fill[dst[e]], 1);
  eid[pos] = e;
}

// ---------------------------------------------------------------------------
// CSR-ordered fused GINE kernel. Block owns 16 dst nodes; walks their incoming
// edges in 64-edge chunks. No global atomics; plain coalesced g1 stores.
// __launch_bounds__(256,3): 50KB LDS caps occupancy at 3 blocks/CU anyway;
// this raises the VGPR cap to ~170 so acc[16] (64 VGPRs) is NOT spilled to
// scratch (VGPR=76 + 1.98GB WRITE_SIZE in round 2 = spill traffic).
// ---------------------------------------------------------------------------
__global__ __launch_bounds__(256, 3) void gine2_kernel(
    const float* __restrict__ edge_attr,
    const int* __restrict__ src_idx, const int* __restrict__ dst_idx,
    const int* __restrict__ row_ptr, const int* __restrict__ eid_sorted,
    const float* __restrict__ ee_w, const float* __restrict__ ee_b,
    const float* __restrict__ elin_w, const float* __restrict__ elin_b,
    const float* __restrict__ h, const float* __restrict__ eps, int layer,
    float* __restrict__ g1)
{
  __shared__ float ea_s[64][5];
  __shared__ int si_s[64];
  __shared__ int sl_s[64];
  __shared__ float EsT[128][64];
  __shared__ float g_acc[16][256];
  const int tid = threadIdx.x;
  const int n0 = blockIdx.x << 4;
#pragma unroll
  for (int i = 0; i < 4; ++i)
    ((float4*)g_acc)[(i << 8) + tid] = make_float4(0.f, 0.f, 0.f, 0.f);
  const int row_start = row_ptr[n0];
  const int row_end = row_ptr[n0 + 16];
  const int cg = (tid & 63) << 2;
  const int eg = (tid >> 6) << 4;
  const float4 b4 = *(const float4*)(elin_b + cg);

  for (int cs = row_start; cs < row_end; cs += 64) {
    __syncthreads();
    if (tid < 64) {
      const int slot = cs + tid;
      float4 v = make_float4(0.f, 0.f, 0.f, 0.f);
      int s = 0, sl = -1;
      if (slot < row_end) {
        const int e = eid_sorted[slot];
        v = *(const float4*)(edge_attr + ((size_t)e << 2));
        s = src_idx[e];
        sl = dst_idx[e] - n0;
      }
      ea_s[tid][0] = v.x; ea_s[tid][1] = v.y;
      ea_s[tid][2] = v.z; ea_s[tid][3] = v.w;
      si_s[tid] = s; sl_s[tid] = sl;
    }
    float4 acc[16];
#pragma unroll
    for (int i = 0; i < 16; ++i) acc[i] = make_float4(0.f, 0.f, 0.f, 0.f);
    __syncthreads();

    for (int kk = 0; kk < 256; kk += 128) {
      {  // stage EsT[k][e]
        const int e = tid & 63;
        const int kb = (tid >> 6) << 5;
        const float a0 = ea_s[e][0], a1 = ea_s[e][1];
        const float a2 = ea_s[e][2], a3 = ea_s[e][3];
#pragma unroll 4
        for (int dk = 0; dk < 32; ++dk) {
          const int kl = kb + dk;
          const int gk = kk + kl;
          float v = ee_b[gk];
          v = fmaf(a0, ee_w[gk], v);
          v = fmaf(a1, ee_w[256 + gk], v);
          v = fmaf(a2, ee_w[512 + gk], v);
          v = fmaf(a3, ee_w[768 + gk], v);
          EsT[kl][e] = fmaxf(v, 0.f);
        }
      }
      __syncthreads();
#pragma unroll 2
      for (int k = 0; k < 128; ++k) {
        const float4 w4 = *(const float4*)(elin_w + (size_t)((kk + k) << 8) + cg);
#pragma unroll
        for (int q = 0; q < 4; ++q) {
          const float4 ev = *(const float4*)&EsT[k][eg + (q << 2)];
          FMA4(acc[(q << 2) + 0], ev.x, w4);
          FMA4(acc[(q << 2) + 1], ev.y, w4);
          FMA4(acc[(q << 2) + 2], ev.z, w4);
          FMA4(acc[(q << 2) + 3], ev.w, w4);
        }
      }
      __syncthreads();
    }

#pragma unroll 4
    for (int i = 0; i < 16; ++i) {
      const int li = eg + i;
      const int sl = sl_s[li];
      if (sl < 0) continue;
      const int s = si_s[li];
      const float4 hv = *(const float4*)(h + (((size_t)s) << 8) + cg);
      const float mx = fmaxf(hv.x + acc[i].x + b4.x, 0.f);
      const float my = fmaxf(hv.y + acc[i].y + b4.y, 0.f);
      const float mz = fmaxf(hv.z + acc[i].z + b4.z, 0.f);
      const float mw = fmaxf(hv.w + acc[i].w + b4.w, 0.f);
      atomicAdd(&g_acc[sl][cg + 0], mx);
      atomicAdd(&g_acc[sl][cg + 1], my);
      atomicAdd(&g_acc[sl][cg + 2], mz);
      atomicAdd(&g_acc[sl][cg + 3], mw);
    }
  }
  __syncthreads();

  const float f = 1.f + eps[layer];
  const int row = tid >> 4;
  const int c0 = (tid & 15) << 4;
  const size_t nb = (((size_t)(n0 + row)) << 8) + c0;
#pragma unroll
  for (int j = 0; j < 4; ++j) {
    const float4 hv = *(const float4*)(h + nb + (j << 2));
    const float4 av = *(const float4*)&g_acc[row][c0 + (j << 2)];
    float4 o;
    o.x = fmaf(f, hv.x, av.x);
    o.y = fmaf(f, hv.y, av.y);
    o.z = fmaf(f, hv.z, av.z);
    o.w = fmaf(f, hv.w, av.w);
    *(float4*)(g1 + nb + (j << 2)) = o;
  }
}

// ---------------------------------------------------------------------------
// Streaming attention, one block per (graph, head). Thread p = query row p.
// __launch_bounds__(256,2): 64KB LDS caps at 2 blocks/CU; VGPR cap 256 keeps
// q[16]+oa[16] (128 VGPRs) in registers.
// ---------------------------------------------------------------------------
__global__ __launch_bounds__(256, 2) void attn_kernel(
    const float* __restrict__ qkv, float* __restrict__ o)
{
  __shared__ float k_s[128][64];
  __shared__ float v_s[128][64];
  const int gh = blockIdx.x;
  const int g = gh >> 2;
  const int hh = gh & 3;
  const int p = threadIdx.x;
  const float scale = 0.125f;
  const float* qrow = qkv + ((size_t)(g * 256 + p)) * 768 + hh * 64;
  float4 q[16];
#pragma unroll
  for (int i = 0; i < 16; ++i) q[i] = *(const float4*)(qrow + (i << 2));
  float4 oa[16];
#pragma unroll
  for (int i = 0; i < 16; ++i) oa[i] = make_float4(0.f, 0.f, 0.f, 0.f);
  float l = 0.f;
  for (int kb = 0; kb < 256; kb += 128) {
    __syncthreads();
#pragma unroll
    for (int it = 0; it < 8; ++it) {
      const int idx = it * 256 + p;
      const int row = idx >> 4;
      const int c4 = (idx & 15) << 2;
      const float* base = qkv + ((size_t)(g * 256 + kb + row)) * 768 + hh * 64 + c4;
      *(float4*)&k_s[row][c4] = *(const float4*)(base + 256);
      *(float4*)&v_s[row][c4] = *(const float4*)(base + 512);
    }
    __syncthreads();
    for (int j = 0; j < 128; ++j) {
      const float* kr = k_s[j];
      float s = 0.f;
#pragma unroll
      for (int i = 0; i < 16; ++i) {
        const float4 kv = *(const float4*)(kr + (i << 2));
        s = fmaf(q[i].x, kv.x, s);
        s = fmaf(q[i].y, kv.y, s);
        s = fmaf(q[i].z, kv.z, s);
        s = fmaf(q[i].w, kv.w, s);
      }
      const float pe = __expf(s * scale);
      l += pe;
      const float* vr = v_s[j];
#pragma unroll
      for (int i = 0; i < 16; ++i) {
        const float4 vv = *(const float4*)(vr + (i << 2));
        FMA4(oa[i], pe, vv);
      }
    }
  }
  const float inv = 1.f / l;
  float* orow = o + ((size_t)(g * 256 + p)) * 256 + hh * 64;
#pragma unroll
  for (int i = 0; i < 16; ++i) {
    float4 t = oa[i];
    t.x *= inv; t.y *= inv; t.z *= inv; t.w *= inv;
    *(float4*)(orow + (i << 2)) = t;
  }
}

// ---------------------------------------------------------------------------
__global__ __launch_bounds__(256) void ln_kernel(
    const float* __restrict__ a, const float* __restrict__ res,
    const float* __restrict__ gam, const float* __restrict__ bet,
    float* __restrict__ out, int relu)
{
  __shared__ float2 red[256];
  const int t = threadIdx.x;
  const size_t base = (size_t)blockIdx.x * 256;
  float v = a[base + t];
  if (res) v += res[base + t];
  red[t] = make_float2(v, v * v);
  __syncthreads();
#pragma unroll
  for (int s = 128; s > 0; s >>= 1) {
    if (t < s) { red[t].x += red[t + s].x; red[t].y += red[t + s].y; }
    __syncthreads();
  }
  const float mu = red[0].x * (1.f / 256.f);
  const float var = red[0].y * (1.f / 256.f) - mu * mu;
  float r = (v - mu) * rsqrtf(var + 1e-5f) * gam[t] + bet[t];
  if (relu) r = fmaxf(r, 0.f);
  out[base + t] = r;
}

__global__ __launch_bounds__(256) void bn_stats_kernel(
    const float* __restrict__ y, float* __restrict__ stats)
{
  const int t = threadIdx.x;
  const size_t r0 = (size_t)blockIdx.x * 64;
  float s = 0.f, s2 = 0.f;
  for (int r = 0; r < 64; ++r) {
    const float v = y[(r0 + r) * 256 + t];
    s += v;
    s2 = fmaf(v, v, s2);
  }
  atomicAdd(&stats[t], s);
  atomicAdd(&stats[256 + t], s2);
}

__global__ __launch_bounds__(256) void bn_apply_kernel(
    float* __restrict__ y, const float* __restrict__ stats,
    const float* __restrict__ gam, const float* __restrict__ bet)
{
  const size_t i = ((size_t)blockIdx.x * 256 + threadIdx.x) << 2;
  const int c = (int)(i & 255);
  const float inv_n = 1.f / 65536.f;
  float4 v = *(float4*)(y + i);
  const float4 s4 = *(const float4*)(stats + c);
  const float4 q4 = *(const float4*)(stats + 256 + c);
  const float4 g4 = *(const float4*)(gam + c);
  const float4 b4 = *(const float4*)(bet + c);
  float mu, var, sc;
  mu = s4.x * inv_n; var = q4.x * inv_n - mu * mu; sc = g4.x * rsqrtf(var + 1e-5f);
  v.x = fmaxf((v.x - mu) * sc + b4.x, 0.f);
  mu = s4.y * inv_n; var = q4.y * inv_n - mu * mu; sc = g4.y * rsqrtf(var + 1e-5f);
  v.y = fmaxf((v.y - mu) * sc + b4.y, 0.f);
  mu = s4.z * inv_n; var = q4.z * inv_n - mu * mu; sc = g4.z * rsqrtf(var + 1e-5f);
  v.z = fmaxf((v.z - mu) * sc + b4.z, 0.f);
  mu = s4.w * inv_n; var = q4.w * inv_n - mu * mu; sc = g4.w * rsqrtf(var + 1e-5f);
  v.w = fmaxf((v.w - mu) * sc + b4.w, 0.f);
  *(float4*)(y + i) = v;
}

__global__ __launch_bounds__(256) void add_kernel(
    const float* __restrict__ a, const float* __restrict__ b,
    float* __restrict__ out)
{
  const size_t i = ((size_t)blockIdx.x * 256 + threadIdx.x) << 2;
  const float4 va = *(const float4*)(a + i);
  const float4 vb = *(const float4*)(b + i);
  float4 v;
  v.x = va.x + vb.x; v.y = va.y + vb.y; v.z = va.z + vb.z; v.w = va.w + vb.w;
  *(float4*)(out + i) = v;
}

__global__ __launch_bounds__(256) void pool_kernel(
    const float* __restrict__ h, const int* __restrict__ batch,
    float* __restrict__ sums, float* __restrict__ cnt)
{
  const int t = threadIdx.x;
  const int n0 = blockIdx.x * 256;
  float acc = 0.f, runc = 0.f;
  int cur = batch[n0];
  for (int r = 0; r < 256; ++r) {
    const int n = n0 + r;
    const int b = batch[n];
    if (b != cur) {
      atomicAdd(&sums[(size_t)cur * 256 + t], acc);
      if (t == 0) atomicAdd(&cnt[cur], runc);
      acc = 0.f; runc = 0.f; cur = b;
    }
    acc += h[(size_t)n * 256 + t];
    runc += 1.f;
  }
  atomicAdd(&sums[(size_t)cur * 256 + t], acc);
  if (t == 0) atomicAdd(&cnt[cur], runc);
}

__global__ __launch_bounds__(256) void gemb_kernel(
    const float* __restrict__ sums, const float* __restrict__ cnt,
    float* __restrict__ gemb)
{
  const int i = blockIdx.x * 256 + threadIdx.x;
  const int g = i >> 8;
  gemb[i] = sums[i] / fmaxf(cnt[g], 1.f);
}

__global__ __launch_bounds__(256) void head_kernel(
    const float* __restrict__ z2, const float* __restrict__ w3,
    const float* __restrict__ b3, float* __restrict__ out)
{
  __shared__ float w[128];
  const int t = threadIdx.x;
  if (t < 128) w[t] = w3[t];
  __syncthreads();
  float s = 0.f;
  const float* row = z2 + (size_t)t * 128;
#pragma unroll 4
  for (int d = 0; d < 128; ++d) s = fmaf(row[d], w[d], s);
  out[t] = s + b3[0];
}

// ---------------------------------------------------------------------------
extern "C" void kernel_launch(void* const* d_in, const int* in_sizes, int n_in,
                              void* d_out, int out_size, void* d_ws, size_t ws_size,
                              hipStream_t stream)
{
  const float* x          = (const float*)d_in[0];
  const int*   edge_index = (const int*)d_in[1];
  const int*   batch      = (const int*)d_in[2];
  const float* edge_attr  = (const float*)d_in[3];
  const float* ne_w   = (const float*)d_in[4];
  const float* ne_b   = (const float*)d_in[5];
  const float* ne_ln_g = (const float*)d_in[6];
  const float* ne_ln_b = (const float*)d_in[7];
  const float* ee_w   = (const float*)d_in[8];
  const float* ee_b   = (const float*)d_in[9];
  const float* eps    = (const float*)d_in[10];
  const float* elin_w = (const float*)d_in[11];
  const float* gin_w1 = (const float*)d_in[12];
  const float* gin_w2 = (const float*)d_in[13];
  const float* attn_in_w  = (const float*)d_in[14];
  const float* attn_out_w = (const float*)d_in[15];
  const float* mlp_w1 = (const float*)d_in[16];
  const float* mlp_w2 = (const float*)d_in[17];
  const float* elin_b = (const float*)d_in[18];
  const float* gin_b1 = (const float*)d_in[19];
  const float* gin_b2 = (const float*)d_in[20];
  const float* attn_in_b  = (const float*)d_in[21];
  const float* attn_out_b = (const float*)d_in[22];
  const float* mlp_b1 = (const float*)d_in[23];
  const float* mlp_b2 = (const float*)d_in[24];
  const float* gin_bn_g = (const float*)d_in[25];
  const float* ln1_g  = (const float*)d_in[26];
  const float* ln2_g  = (const float*)d_in[27];
  const float* ln3_g  = (const float*)d_in[28];
  const float* gin_bn_b = (const float*)d_in[29];
  const float* ln1_b  = (const float*)d_in[30];
  const float* ln2_b  = (const float*)d_in[31];
  const float* ln3_b  = (const float*)d_in[32];
  const float* cls_w1 = (const float*)d_in[33];
  const float* cls_b1 = (const float*)d_in[34];
  const float* cls_ln_g = (const float*)d_in[35];
  const float* cls_ln_b = (const float*)d_in[36];
  const float* cls_w2 = (const float*)d_in[37];
  const float* cls_b2 = (const float*)d_in[38];
  const float* cls_w3 = (const float*)d_in[39];
  const float* cls_b3 = (const float*)d_in[40];

  const int* src = edge_index;
  const int* dst = edge_index + N_EDGES;

  float* ws = (float*)d_ws;
  const size_t NC = (size_t)N_NODES * CH;       // 16,777,216
  float* h    = ws;
  float* bufA = ws + NC;                        // g1 -> attn o   (dead post-loop)
  float* bufB = ws + 2 * NC;
  float* bufC = ws + 3 * NC;
  float* bufQ = ws + 4 * NC;                    // qkv [N,768] -> m1 [N,512]
  float* stats = bufQ + (size_t)N_NODES * 768;  // 4*512
  int* ideg  = (int*)(stats + 2048);            // 65536
  int* ifill = ideg + 65536;                    // 65536
  int* irow  = ifill + 65536;                   // 65537 (padded to 65544)
  int* ieid  = irow + 65544;                    // 524288
  // post-loop scratch reuses bufA (dead after last layer):
  float* sums = bufA;                           // 65536
  float* cnt  = bufA + 65536;                   // 256
  float* gemb = bufA + 65792;                   // 65536
  float* z1   = bufA + 131328;                  // 65536
  float* z2   = bufA + 196864;                  // 32768

  const dim3 blk(256);

  // ---- CSR build (once; reused by all 4 layers) ----
  hipMemsetAsync(stats, 0, 2048 * sizeof(float), stream);
  hipMemsetAsync(ideg, 0, 65536 * sizeof(int), stream);
  hist_kernel<<<dim3(2048), blk, 0, stream>>>(dst, ideg);
  scan_kernel<<<dim3(1), blk, 0, stream>>>(ideg, irow, ifill);
  scatter_kernel<<<dim3(2048), blk, 0, stream>>>(dst, ifill, ieid);

  // ---- encoders ----
  gemm_kernel<false, false><<<dim3(2, 512), blk, 0, stream>>>(
      x, ne_w, ne_b, bufB, N_NODES, 256, 771);
  ln_kernel<<<dim3(N_NODES), blk, 0, stream>>>(bufB, nullptr, ne_ln_g, ne_ln_b, h, 1);

  for (int l = 0; l < 4; ++l) {
    // ---- GINEConv (fused (1+eps)*h + sorted no-atomic aggregation) ----
    gine2_kernel<<<dim3(4096), blk, 0, stream>>>(
        edge_attr, src, dst, irow, ieid, ee_w, ee_b,
        elin_w + (size_t)l * 65536, elin_b + l * 256, h, eps, l, bufA);
    gemm_kernel<false, false><<<dim3(2, 512), blk, 0, stream>>>(
        bufA, gin_w1 + (size_t)l * 65536, gin_b1 + l * 256, bufB, N_NODES, 256, 256);
    bn_stats_kernel<<<dim3(1024), blk, 0, stream>>>(bufB, stats + l * 512);
    bn_apply_kernel<<<dim3(16384), blk, 0, stream>>>(
        bufB, stats + l * 512, gin_bn_g + l * 256, gin_bn_b + l * 256);
    gemm_kernel<false, false><<<dim3(2, 512), blk, 0, stream>>>(
        bufB, gin_w2 + (size_t)l * 65536, gin_b2 + l * 256, bufC, N_NODES, 256, 256);
    ln_kernel<<<dim3(N_NODES), blk, 0, stream>>>(
        bufC, h, ln1_g + l * 256, ln1_b + l * 256, bufC, 0);
    // ---- attention ----
    gemm_kernel<true, false><<<dim3(6, 512), blk, 0, stream>>>(
        h, attn_in_w + (size_t)l * 768 * 256, attn_in_b + l * 768, bufQ,
        N_NODES, 768, 256);
    attn_kernel<<<dim3(1024), blk, 0, stream>>>(bufQ, bufA);
    gemm_kernel<true, false><<<dim3(2, 512), blk, 0, stream>>>(
        bufA, attn_out_w + (size_t)l * 65536, attn_out_b + l * 256, bufB,
        N_NODES, 256, 256);
    ln_kernel<<<dim3(N_NODES), blk, 0, stream>>>(
        bufB, h, ln2_g + l * 256, ln2_b + l * 256, bufB, 0);
    // ---- FFN ----
    add_kernel<<<dim3(16384), blk, 0, stream>>>(bufC, bufB, bufB);
    gemm_kernel<false, true><<<dim3(4, 512), blk, 0, stream>>>(
        bufB, mlp_w1 + (size_t)l * 256 * 512, mlp_b1 + l * 512, bufQ,
        N_NODES, 512, 256);
    gemm_kernel<false, false><<<dim3(2, 512), blk, 0, stream>>>(
        bufQ, mlp_w2 + (size_t)l * 512 * 256, mlp_b2 + l * 256, bufC,
        N_NODES, 256, 512);
    ln_kernel<<<dim3(N_NODES), blk, 0, stream>>>(
        bufC, bufB, ln3_g + l * 256, ln3_b + l * 256, h, 0);
  }

  // ---- pooling + classifier (bufA reused as scratch; dead otherwise) ----
  hipMemsetAsync(sums, 0, 65792 * sizeof(float), stream);
  pool_kernel<<<dim3(256), blk, 0, stream>>>(h, batch, sums, cnt);
  gemb_kernel<<<dim3(256), blk, 0, stream>>>(sums, cnt, gemb);
  gemm_kernel<false, false><<<dim3(2, 2), blk, 0, stream>>>(
      gemb, cls_w1, cls_b1, z1, 256, 256, 256);
  ln_kernel<<<dim3(256), blk, 0, stream>>>(z1, nullptr, cls_ln_g, cls_ln_b, z1, 1);
  gemm_kernel<false, true><<<dim3(1, 2), blk, 0, stream>>>(
      z1, cls_w2, cls_b2, z2, 256, 128, 256);
  head_kernel<<<dim3(1), blk, 0, stream>>>(z2, cls_w3, cls_b3, (float*)d_out);
}

// Round 4
// 15713.872 us; speedup vs baseline: 1.0255x; 1.0255x over previous
//
#include <hip/hip_runtime.h>
#include <math.h>

#define N_NODES 65536
#define N_EDGES 524288
#define CH 256

#define FMA4(A4, S, W4) \
  A4.x = fmaf((S), (W4).x, A4.x); A4.y = fmaf((S), (W4).y, A4.y); \
  A4.z = fmaf((S), (W4).z, A4.z); A4.w = fmaf((S), (W4).w, A4.w)

// ---------------------------------------------------------------------------
// Generic tiled fp32 GEMM: C[M,N] = A[M,K] @ B + bias (+relu)
// BT=false: B is [K,N] row-major.  BT=true: B is [N,K] row-major (C = A@B^T).
// 128x128 tile, 256 threads, 8x8 per thread, K-chunks of 8.
// ---------------------------------------------------------------------------
template <bool BT, bool RELU>
__global__ __launch_bounds__(256, 4) void gemm_kernel(
    const float* __restrict__ A, const float* __restrict__ B,
    const float* __restrict__ bias, float* __restrict__ Cmat,
    int M, int Nn, int K)
{
  __shared__ float As[8][132];
  __shared__ float Bs[8][132];
  const int tid = threadIdx.x;
  const int bm = blockIdx.y * 128;
  const int bn = blockIdx.x * 128;
  const int tm = (tid >> 4) << 3;
  const int tn = (tid & 15) << 3;
  float acc[8][8];
#pragma unroll
  for (int i = 0; i < 8; ++i)
#pragma unroll
    for (int j = 0; j < 8; ++j) acc[i][j] = 0.f;

  const int nk = (K + 7) >> 3;
  const bool k4 = (K & 3) == 0;
  for (int kc = 0; kc < nk; ++kc) {
    const int k0 = kc << 3;
    {  // stage A: As[k][m] = A[bm+m][k0+k]
      const int r = tid >> 1;
      const int kk = (tid & 1) << 2;
      const int gm = bm + r;
      float va[4] = {0.f, 0.f, 0.f, 0.f};
      if (gm < M) {
        const size_t base = (size_t)gm * K + k0 + kk;
        if (k4 && (k0 + kk + 4 <= K)) {
          const float4 v = *(const float4*)(A + base);
          va[0] = v.x; va[1] = v.y; va[2] = v.z; va[3] = v.w;
        } else {
#pragma unroll
          for (int j = 0; j < 4; ++j)
            if (k0 + kk + j < K) va[j] = A[base + j];
        }
      }
      As[kk + 0][r] = va[0]; As[kk + 1][r] = va[1];
      As[kk + 2][r] = va[2]; As[kk + 3][r] = va[3];
    }
    if (!BT) {
      const int r = tid >> 5;
      const int cb = (tid & 31) << 2;
      float4 v = make_float4(0.f, 0.f, 0.f, 0.f);
      if (k0 + r < K) v = *(const float4*)(B + (size_t)(k0 + r) * Nn + bn + cb);
      *(float4*)&Bs[r][cb] = v;
    } else {
      const int r = tid >> 1;
      const int kk = (tid & 1) << 2;
      float vb[4] = {0.f, 0.f, 0.f, 0.f};
      if (bn + r < Nn) {
        const size_t base = (size_t)(bn + r) * K + k0 + kk;
        if (k4 && (k0 + kk + 4 <= K)) {
          const float4 v = *(const float4*)(B + base);
          vb[0] = v.x; vb[1] = v.y; vb[2] = v.z; vb[3] = v.w;
        } else {
#pragma unroll
          for (int j = 0; j < 4; ++j)
            if (k0 + kk + j < K) vb[j] = B[base + j];
        }
      }
      Bs[kk + 0][r] = vb[0]; Bs[kk + 1][r] = vb[1];
      Bs[kk + 2][r] = vb[2]; Bs[kk + 3][r] = vb[3];
    }
    __syncthreads();
#pragma unroll
    for (int k = 0; k < 8; ++k) {
      const float4 a0 = *(const float4*)&As[k][tm];
      const float4 a1 = *(const float4*)&As[k][tm + 4];
      const float4 b0 = *(const float4*)&Bs[k][tn];
      const float4 b1 = *(const float4*)&Bs[k][tn + 4];
      const float av[8] = {a0.x, a0.y, a0.z, a0.w, a1.x, a1.y, a1.z, a1.w};
      const float bv[8] = {b0.x, b0.y, b0.z, b0.w, b1.x, b1.y, b1.z, b1.w};
#pragma unroll
      for (int i = 0; i < 8; ++i)
#pragma unroll
        for (int j = 0; j < 8; ++j)
          acc[i][j] = fmaf(av[i], bv[j], acc[i][j]);
    }
    __syncthreads();
  }
#pragma unroll
  for (int i = 0; i < 8; ++i) {
    const int gm = bm + tm + i;
    if (gm >= M) continue;
    float* crow = Cmat + (size_t)gm * Nn + bn + tn;
#pragma unroll
    for (int j = 0; j < 8; ++j) {
      const int gn = bn + tn + j;
      if (gn >= Nn) continue;
      float v = acc[i][j] + (bias ? bias[gn] : 0.f);
      if (RELU) v = fmaxf(v, 0.f);
      crow[j] = v;
    }
  }
}

// ---------------------------------------------------------------------------
// CSR build: histogram of dst -> exclusive scan -> scatter edge ids.
// ---------------------------------------------------------------------------
__global__ __launch_bounds__(256) void hist_kernel(
    const int* __restrict__ dst, int* __restrict__ deg)
{
  const int e = blockIdx.x * 256 + threadIdx.x;
  atomicAdd(&deg[dst[e]], 1);
}

__global__ __launch_bounds__(256) void scan_kernel(
    const int* __restrict__ deg, int* __restrict__ row_ptr,
    int* __restrict__ fill)
{
  __shared__ int part[256];
  const int t = threadIdx.x;
  const int base = t << 8;
  int s = 0;
  for (int j = 0; j < 256; ++j) s += deg[base + j];
  part[t] = s;
  __syncthreads();
  for (int off = 1; off < 256; off <<= 1) {
    int v = (t >= off) ? part[t - off] : 0;
    __syncthreads();
    part[t] += v;
    __syncthreads();
  }
  int run = (t == 0) ? 0 : part[t - 1];
  for (int j = 0; j < 256; ++j) {
    row_ptr[base + j] = run;
    fill[base + j] = run;
    run += deg[base + j];
  }
  if (t == 255) row_ptr[65536] = run;
}

__global__ __launch_bounds__(256) void scatter_kernel(
    const int* __restrict__ dst, int* __restrict__ fill,
    int* __restrict__ eid)
{
  const int e = blockIdx.x * 256 + threadIdx.x;
  const int pos = atomicAdd(&fill[dst[e]], 1);
  eid[pos] = e;
}

// ---------------------------------------------------------------------------
// CSR-ordered fused GINE kernel. Block owns 16 dst nodes; walks their incoming
// edges in 64-edge chunks. No global atomics; plain coalesced g1 stores.
// NOTE: every loop touching acc[] must be FULLY unrolled — a partial unroll
// (runtime index) forces the whole array into scratch (round 2/3: VGPR=76,
// 1.98GB WRITE_SIZE of scratch evictions, VALUBusy 37%).
// ---------------------------------------------------------------------------
__global__ __launch_bounds__(256, 3) void gine2_kernel(
    const float* __restrict__ edge_attr,
    const int* __restrict__ src_idx, const int* __restrict__ dst_idx,
    const int* __restrict__ row_ptr, const int* __restrict__ eid_sorted,
    const float* __restrict__ ee_w, const float* __restrict__ ee_b,
    const float* __restrict__ elin_w, const float* __restrict__ elin_b,
    const float* __restrict__ h, const float* __restrict__ eps, int layer,
    float* __restrict__ g1)
{
  __shared__ float ea_s[64][5];
  __shared__ int si_s[64];
  __shared__ int sl_s[64];
  __shared__ float EsT[128][64];
  __shared__ float g_acc[16][256];
  const int tid = threadIdx.x;
  const int n0 = blockIdx.x << 4;
#pragma unroll
  for (int i = 0; i < 4; ++i)
    ((float4*)g_acc)[(i << 8) + tid] = make_float4(0.f, 0.f, 0.f, 0.f);
  const int row_start = row_ptr[n0];
  const int row_end = row_ptr[n0 + 16];
  const int cg = (tid & 63) << 2;
  const int eg = (tid >> 6) << 4;
  const float4 b4 = *(const float4*)(elin_b + cg);

  for (int cs = row_start; cs < row_end; cs += 64) {
    __syncthreads();
    if (tid < 64) {
      const int slot = cs + tid;
      float4 v = make_float4(0.f, 0.f, 0.f, 0.f);
      int s = 0, sl = -1;
      if (slot < row_end) {
        const int e = eid_sorted[slot];
        v = *(const float4*)(edge_attr + ((size_t)e << 2));
        s = src_idx[e];
        sl = dst_idx[e] - n0;
      }
      ea_s[tid][0] = v.x; ea_s[tid][1] = v.y;
      ea_s[tid][2] = v.z; ea_s[tid][3] = v.w;
      si_s[tid] = s; sl_s[tid] = sl;
    }
    float4 acc[16];
#pragma unroll
    for (int i = 0; i < 16; ++i) acc[i] = make_float4(0.f, 0.f, 0.f, 0.f);
    __syncthreads();

    for (int kk = 0; kk < 256; kk += 128) {
      {  // stage EsT[k][e]
        const int e = tid & 63;
        const int kb = (tid >> 6) << 5;
        const float a0 = ea_s[e][0], a1 = ea_s[e][1];
        const float a2 = ea_s[e][2], a3 = ea_s[e][3];
#pragma unroll 4
        for (int dk = 0; dk < 32; ++dk) {
          const int kl = kb + dk;
          const int gk = kk + kl;
          float v = ee_b[gk];
          v = fmaf(a0, ee_w[gk], v);
          v = fmaf(a1, ee_w[256 + gk], v);
          v = fmaf(a2, ee_w[512 + gk], v);
          v = fmaf(a3, ee_w[768 + gk], v);
          EsT[kl][e] = fmaxf(v, 0.f);
        }
      }
      __syncthreads();
#pragma unroll 2
      for (int k = 0; k < 128; ++k) {
        const float4 w4 = *(const float4*)(elin_w + (size_t)((kk + k) << 8) + cg);
#pragma unroll
        for (int q = 0; q < 4; ++q) {
          const float4 ev = *(const float4*)&EsT[k][eg + (q << 2)];
          FMA4(acc[(q << 2) + 0], ev.x, w4);
          FMA4(acc[(q << 2) + 1], ev.y, w4);
          FMA4(acc[(q << 2) + 2], ev.z, w4);
          FMA4(acc[(q << 2) + 3], ev.w, w4);
        }
      }
      __syncthreads();
    }

    // FULL unroll: acc[i] must be a compile-time index (see kernel note).
#pragma unroll
    for (int i = 0; i < 16; ++i) {
      const int li = eg + i;
      const int sl = sl_s[li];
      if (sl < 0) continue;
      const int s = si_s[li];
      const float4 hv = *(const float4*)(h + (((size_t)s) << 8) + cg);
      const float mx = fmaxf(hv.x + acc[i].x + b4.x, 0.f);
      const float my = fmaxf(hv.y + acc[i].y + b4.y, 0.f);
      const float mz = fmaxf(hv.z + acc[i].z + b4.z, 0.f);
      const float mw = fmaxf(hv.w + acc[i].w + b4.w, 0.f);
      atomicAdd(&g_acc[sl][cg + 0], mx);
      atomicAdd(&g_acc[sl][cg + 1], my);
      atomicAdd(&g_acc[sl][cg + 2], mz);
      atomicAdd(&g_acc[sl][cg + 3], mw);
    }
  }
  __syncthreads();

  const float f = 1.f + eps[layer];
  const int row = tid >> 4;
  const int c0 = (tid & 15) << 4;
  const size_t nb = (((size_t)(n0 + row)) << 8) + c0;
#pragma unroll
  for (int j = 0; j < 4; ++j) {
    const float4 hv = *(const float4*)(h + nb + (j << 2));
    const float4 av = *(const float4*)&g_acc[row][c0 + (j << 2)];
    float4 o;
    o.x = fmaf(f, hv.x, av.x);
    o.y = fmaf(f, hv.y, av.y);
    o.z = fmaf(f, hv.z, av.z);
    o.w = fmaf(f, hv.w, av.w);
    *(float4*)(g1 + nb + (j << 2)) = o;
  }
}

// ---------------------------------------------------------------------------
// Streaming attention, one block per (graph, head). Thread p = query row p.
// All q[]/oa[] loops are FULL unrolls (scratch-avoidance, see gine2 note).
// ---------------------------------------------------------------------------
__global__ __launch_bounds__(256, 2) void attn_kernel(
    const float* __restrict__ qkv, float* __restrict__ o)
{
  __shared__ float k_s[128][64];
  __shared__ float v_s[128][64];
  const int gh = blockIdx.x;
  const int g = gh >> 2;
  const int hh = gh & 3;
  const int p = threadIdx.x;
  const float scale = 0.125f;
  const float* qrow = qkv + ((size_t)(g * 256 + p)) * 768 + hh * 64;
  float4 q[16];
#pragma unroll
  for (int i = 0; i < 16; ++i) q[i] = *(const float4*)(qrow + (i << 2));
  float4 oa[16];
#pragma unroll
  for (int i = 0; i < 16; ++i) oa[i] = make_float4(0.f, 0.f, 0.f, 0.f);
  float l = 0.f;
  for (int kb = 0; kb < 256; kb += 128) {
    __syncthreads();
#pragma unroll
    for (int it = 0; it < 8; ++it) {
      const int idx = it * 256 + p;
      const int row = idx >> 4;
      const int c4 = (idx & 15) << 2;
      const float* base = qkv + ((size_t)(g * 256 + kb + row)) * 768 + hh * 64 + c4;
      *(float4*)&k_s[row][c4] = *(const float4*)(base + 256);
      *(float4*)&v_s[row][c4] = *(const float4*)(base + 512);
    }
    __syncthreads();
    for (int j = 0; j < 128; ++j) {
      const float* kr = k_s[j];
      float s = 0.f;
#pragma unroll
      for (int i = 0; i < 16; ++i) {
        const float4 kv = *(const float4*)(kr + (i << 2));
        s = fmaf(q[i].x, kv.x, s);
        s = fmaf(q[i].y, kv.y, s);
        s = fmaf(q[i].z, kv.z, s);
        s = fmaf(q[i].w, kv.w, s);
      }
      const float pe = __expf(s * scale);
      l += pe;
      const float* vr = v_s[j];
#pragma unroll
      for (int i = 0; i < 16; ++i) {
        const float4 vv = *(const float4*)(vr + (i << 2));
        FMA4(oa[i], pe, vv);
      }
    }
  }
  const float inv = 1.f / l;
  float* orow = o + ((size_t)(g * 256 + p)) * 256 + hh * 64;
#pragma unroll
  for (int i = 0; i < 16; ++i) {
    float4 t = oa[i];
    t.x *= inv; t.y *= inv; t.z *= inv; t.w *= inv;
    *(float4*)(orow + (i << 2)) = t;
  }
}

// ---------------------------------------------------------------------------
__global__ __launch_bounds__(256) void ln_kernel(
    const float* __restrict__ a, const float* __restrict__ res,
    const float* __restrict__ gam, const float* __restrict__ bet,
    float* __restrict__ out, int relu)
{
  __shared__ float2 red[256];
  const int t = threadIdx.x;
  const size_t base = (size_t)blockIdx.x * 256;
  float v = a[base + t];
  if (res) v += res[base + t];
  red[t] = make_float2(v, v * v);
  __syncthreads();
#pragma unroll
  for (int s = 128; s > 0; s >>= 1) {
    if (t < s) { red[t].x += red[t + s].x; red[t].y += red[t + s].y; }
    __syncthreads();
  }
  const float mu = red[0].x * (1.f / 256.f);
  const float var = red[0].y * (1.f / 256.f) - mu * mu;
  float r = (v - mu) * rsqrtf(var + 1e-5f) * gam[t] + bet[t];
  if (relu) r = fmaxf(r, 0.f);
  out[base + t] = r;
}

__global__ __launch_bounds__(256) void bn_stats_kernel(
    const float* __restrict__ y, float* __restrict__ stats)
{
  const int t = threadIdx.x;
  const size_t r0 = (size_t)blockIdx.x * 64;
  float s = 0.f, s2 = 0.f;
  for (int r = 0; r < 64; ++r) {
    const float v = y[(r0 + r) * 256 + t];
    s += v;
    s2 = fmaf(v, v, s2);
  }
  atomicAdd(&stats[t], s);
  atomicAdd(&stats[256 + t], s2);
}

__global__ __launch_bounds__(256) void bn_apply_kernel(
    float* __restrict__ y, const float* __restrict__ stats,
    const float* __restrict__ gam, const float* __restrict__ bet)
{
  const size_t i = ((size_t)blockIdx.x * 256 + threadIdx.x) << 2;
  const int c = (int)(i & 255);
  const float inv_n = 1.f / 65536.f;
  float4 v = *(float4*)(y + i);
  const float4 s4 = *(const float4*)(stats + c);
  const float4 q4 = *(const float4*)(stats + 256 + c);
  const float4 g4 = *(const float4*)(gam + c);
  const float4 b4 = *(const float4*)(bet + c);
  float mu, var, sc;
  mu = s4.x * inv_n; var = q4.x * inv_n - mu * mu; sc = g4.x * rsqrtf(var + 1e-5f);
  v.x = fmaxf((v.x - mu) * sc + b4.x, 0.f);
  mu = s4.y * inv_n; var = q4.y * inv_n - mu * mu; sc = g4.y * rsqrtf(var + 1e-5f);
  v.y = fmaxf((v.y - mu) * sc + b4.y, 0.f);
  mu = s4.z * inv_n; var = q4.z * inv_n - mu * mu; sc = g4.z * rsqrtf(var + 1e-5f);
  v.z = fmaxf((v.z - mu) * sc + b4.z, 0.f);
  mu = s4.w * inv_n; var = q4.w * inv_n - mu * mu; sc = g4.w * rsqrtf(var + 1e-5f);
  v.w = fmaxf((v.w - mu) * sc + b4.w, 0.f);
  *(float4*)(y + i) = v;
}

__global__ __launch_bounds__(256) void add_kernel(
    const float* __restrict__ a, const float* __restrict__ b,
    float* __restrict__ out)
{
  const size_t i = ((size_t)blockIdx.x * 256 + threadIdx.x) << 2;
  const float4 va = *(const float4*)(a + i);
  const float4 vb = *(const float4*)(b + i);
  float4 v;
  v.x = va.x + vb.x; v.y = va.y + vb.y; v.z = va.z + vb.z; v.w = va.w + vb.w;
  *(float4*)(out + i) = v;
}

__global__ __launch_bounds__(256) void pool_kernel(
    const float* __restrict__ h, const int* __restrict__ batch,
    float* __restrict__ sums, float* __restrict__ cnt)
{
  const int t = threadIdx.x;
  const int n0 = blockIdx.x * 256;
  float acc = 0.f, runc = 0.f;
  int cur = batch[n0];
  for (int r = 0; r < 256; ++r) {
    const int n = n0 + r;
    const int b = batch[n];
    if (b != cur) {
      atomicAdd(&sums[(size_t)cur * 256 + t], acc);
      if (t == 0) atomicAdd(&cnt[cur], runc);
      acc = 0.f; runc = 0.f; cur = b;
    }
    acc += h[(size_t)n * 256 + t];
    runc += 1.f;
  }
  atomicAdd(&sums[(size_t)cur * 256 + t], acc);
  if (t == 0) atomicAdd(&cnt[cur], runc);
}

__global__ __launch_bounds__(256) void gemb_kernel(
    const float* __restrict__ sums, const float* __restrict__ cnt,
    float* __restrict__ gemb)
{
  const int i = blockIdx.x * 256 + threadIdx.x;
  const int g = i >> 8;
  gemb[i] = sums[i] / fmaxf(cnt[g], 1.f);
}

__global__ __launch_bounds__(256) void head_kernel(
    const float* __restrict__ z2, const float* __restrict__ w3,
    const float* __restrict__ b3, float* __restrict__ out)
{
  __shared__ float w[128];
  const int t = threadIdx.x;
  if (t < 128) w[t] = w3[t];
  __syncthreads();
  float s = 0.f;
  const float* row = z2 + (size_t)t * 128;
#pragma unroll 4
  for (int d = 0; d < 128; ++d) s = fmaf(row[d], w[d], s);
  out[t] = s + b3[0];
}

// ---------------------------------------------------------------------------
extern "C" void kernel_launch(void* const* d_in, const int* in_sizes, int n_in,
                              void* d_out, int out_size, void* d_ws, size_t ws_size,
                              hipStream_t stream)
{
  const float* x          = (const float*)d_in[0];
  const int*   edge_index = (const int*)d_in[1];
  const int*   batch      = (const int*)d_in[2];
  const float* edge_attr  = (const float*)d_in[3];
  const float* ne_w   = (const float*)d_in[4];
  const float* ne_b   = (const float*)d_in[5];
  const float* ne_ln_g = (const float*)d_in[6];
  const float* ne_ln_b = (const float*)d_in[7];
  const float* ee_w   = (const float*)d_in[8];
  const float* ee_b   = (const float*)d_in[9];
  const float* eps    = (const float*)d_in[10];
  const float* elin_w = (const float*)d_in[11];
  const float* gin_w1 = (const float*)d_in[12];
  const float* gin_w2 = (const float*)d_in[13];
  const float* attn_in_w  = (const float*)d_in[14];
  const float* attn_out_w = (const float*)d_in[15];
  const float* mlp_w1 = (const float*)d_in[16];
  const float* mlp_w2 = (const float*)d_in[17];
  const float* elin_b = (const float*)d_in[18];
  const float* gin_b1 = (const float*)d_in[19];
  const float* gin_b2 = (const float*)d_in[20];
  const float* attn_in_b  = (const float*)d_in[21];
  const float* attn_out_b = (const float*)d_in[22];
  const float* mlp_b1 = (const float*)d_in[23];
  const float* mlp_b2 = (const float*)d_in[24];
  const float* gin_bn_g = (const float*)d_in[25];
  const float* ln1_g  = (const float*)d_in[26];
  const float* ln2_g  = (const float*)d_in[27];
  const float* ln3_g  = (const float*)d_in[28];
  const float* gin_bn_b = (const float*)d_in[29];
  const float* ln1_b  = (const float*)d_in[30];
  const float* ln2_b  = (const float*)d_in[31];
  const float* ln3_b  = (const float*)d_in[32];
  const float* cls_w1 = (const float*)d_in[33];
  const float* cls_b1 = (const float*)d_in[34];
  const float* cls_ln_g = (const float*)d_in[35];
  const float* cls_ln_b = (const float*)d_in[36];
  const float* cls_w2 = (const float*)d_in[37];
  const float* cls_b2 = (const float*)d_in[38];
  const float* cls_w3 = (const float*)d_in[39];
  const float* cls_b3 = (const float*)d_in[40];

  const int* src = edge_index;
  const int* dst = edge_index + N_EDGES;

  float* ws = (float*)d_ws;
  const size_t NC = (size_t)N_NODES * CH;       // 16,777,216
  float* h    = ws;
  float* bufA = ws + NC;                        // g1 -> attn o   (dead post-loop)
  float* bufB = ws + 2 * NC;
  float* bufC = ws + 3 * NC;
  float* bufQ = ws + 4 * NC;                    // qkv [N,768] -> m1 [N,512]
  float* stats = bufQ + (size_t)N_NODES * 768;  // 4*512
  int* ideg  = (int*)(stats + 2048);            // 65536
  int* ifill = ideg + 65536;                    // 65536
  int* irow  = ifill + 65536;                   // 65537 (padded to 65544)
  int* ieid  = irow + 65544;                    // 524288
  // post-loop scratch reuses bufA (dead after last layer):
  float* sums = bufA;                           // 65536
  float* cnt  = bufA + 65536;                   // 256
  float* gemb = bufA + 65792;                   // 65536
  float* z1   = bufA + 131328;                  // 65536
  float* z2   = bufA + 196864;                  // 32768

  const dim3 blk(256);

  // ---- CSR build (once; reused by all 4 layers) ----
  hipMemsetAsync(stats, 0, 2048 * sizeof(float), stream);
  hipMemsetAsync(ideg, 0, 65536 * sizeof(int), stream);
  hist_kernel<<<dim3(2048), blk, 0, stream>>>(dst, ideg);
  scan_kernel<<<dim3(1), blk, 0, stream>>>(ideg, irow, ifill);
  scatter_kernel<<<dim3(2048), blk, 0, stream>>>(dst, ifill, ieid);

  // ---- encoders ----
  gemm_kernel<false, false><<<dim3(2, 512), blk, 0, stream>>>(
      x, ne_w, ne_b, bufB, N_NODES, 256, 771);
  ln_kernel<<<dim3(N_NODES), blk, 0, stream>>>(bufB, nullptr, ne_ln_g, ne_ln_b, h, 1);

  for (int l = 0; l < 4; ++l) {
    // ---- GINEConv (fused (1+eps)*h + sorted no-atomic aggregation) ----
    gine2_kernel<<<dim3(4096), blk, 0, stream>>>(
        edge_attr, src, dst, irow, ieid, ee_w, ee_b,
        elin_w + (size_t)l * 65536, elin_b + l * 256, h, eps, l, bufA);
    gemm_kernel<false, false><<<dim3(2, 512), blk, 0, stream>>>(
        bufA, gin_w1 + (size_t)l * 65536, gin_b1 + l * 256, bufB, N_NODES, 256, 256);
    bn_stats_kernel<<<dim3(1024), blk, 0, stream>>>(bufB, stats + l * 512);
    bn_apply_kernel<<<dim3(16384), blk, 0, stream>>>(
        bufB, stats + l * 512, gin_bn_g + l * 256, gin_bn_b + l * 256);
    gemm_kernel<false, false><<<dim3(2, 512), blk, 0, stream>>>(
        bufB, gin_w2 + (size_t)l * 65536, gin_b2 + l * 256, bufC, N_NODES, 256, 256);
    ln_kernel<<<dim3(N_NODES), blk, 0, stream>>>(
        bufC, h, ln1_g + l * 256, ln1_b + l * 256, bufC, 0);
    // ---- attention ----
    gemm_kernel<true, false><<<dim3(6, 512), blk, 0, stream>>>(
        h, attn_in_w + (size_t)l * 768 * 256, attn_in_b + l * 768, bufQ,
        N_NODES, 768, 256);
    attn_kernel<<<dim3(1024), blk, 0, stream>>>(bufQ, bufA);
    gemm_kernel<true, false><<<dim3(2, 512), blk, 0, stream>>>(
        bufA, attn_out_w + (size_t)l * 65536, attn_out_b + l * 256, bufB,
        N_NODES, 256, 256);
    ln_kernel<<<dim3(N_NODES), blk, 0, stream>>>(
        bufB, h, ln2_g + l * 256, ln2_b + l * 256, bufB, 0);
    // ---- FFN ----
    add_kernel<<<dim3(16384), blk, 0, stream>>>(bufC, bufB, bufB);
    gemm_kernel<false, true><<<dim3(4, 512), blk, 0, stream>>>(
        bufB, mlp_w1 + (size_t)l * 256 * 512, mlp_b1 + l * 512, bufQ,
        N_NODES, 512, 256);
    gemm_kernel<false, false><<<dim3(2, 512), blk, 0, stream>>>(
        bufQ, mlp_w2 + (size_t)l * 512 * 256, mlp_b2 + l * 256, bufC,
        N_NODES, 256, 512);
    ln_kernel<<<dim3(N_NODES), blk, 0, stream>>>(
        bufC, bufB, ln3_g + l * 256, ln3_b + l * 256, h, 0);
  }

  // ---- pooling + classifier (bufA reused as scratch; dead otherwise) ----
  hipMemsetAsync(sums, 0, 65792 * sizeof(float), stream);
  pool_kernel<<<dim3(256), blk, 0, stream>>>(h, batch, sums, cnt);
  gemb_kernel<<<dim3(256), blk, 0, stream>>>(sums, cnt, gemb);
  gemm_kernel<false, false><<<dim3(2, 2), blk, 0, stream>>>(
      gemb, cls_w1, cls_b1, z1, 256, 256, 256);
  ln_kernel<<<dim3(256), blk, 0, stream>>>(z1, nullptr, cls_ln_g, cls_ln_b, z1, 1);
  gemm_kernel<false, true><<<dim3(1, 2), blk, 0, stream>>>(
      z1, cls_w2, cls_b2, z2, 256, 128, 256);
  head_kernel<<<dim3(1), blk, 0, stream>>>(z2, cls_w3, cls_b3, (float*)d_out);
}

// Round 5
// 12505.432 us; speedup vs baseline: 1.2886x; 1.2566x over previous
//
#include <hip/hip_runtime.h>
#include <hip/hip_bf16.h>
#include <math.h>

#define N_NODES 65536
#define N_EDGES 524288
#define CH 256

#define FMA4(A4, S, W4) \
  A4.x = fmaf((S), (W4).x, A4.x); A4.y = fmaf((S), (W4).y, A4.y); \
  A4.z = fmaf((S), (W4).z, A4.z); A4.w = fmaf((S), (W4).w, A4.w)

typedef __bf16 bf16x8 __attribute__((ext_vector_type(8)));
typedef float f32x4 __attribute__((ext_vector_type(4)));

__device__ inline bf16x8 pack_bf16_8(const float4 a, const float4 b) {
  union { __hip_bfloat162 h2[4]; bf16x8 v; } r;
  r.h2[0] = __float22bfloat162_rn(make_float2(a.x, a.y));
  r.h2[1] = __float22bfloat162_rn(make_float2(a.z, a.w));
  r.h2[2] = __float22bfloat162_rn(make_float2(b.x, b.y));
  r.h2[3] = __float22bfloat162_rn(make_float2(b.z, b.w));
  return r.v;
}

// ---------------------------------------------------------------------------
// Weight pre-convert: fp32 W -> bf16 k-panel layout P[(k>>3)*N + n][k&7].
// transposed=1 means logical B[k][n] = W[n*K+k] (for reference's @ W.T GEMMs).
// ---------------------------------------------------------------------------
__global__ __launch_bounds__(256) void wcvt_kernel(
    const float* __restrict__ W, unsigned short* __restrict__ P,
    int K, int Nn, int transposed)
{
  const int idx = blockIdx.x * 256 + threadIdx.x;
  const int k = idx / Nn;
  const int n = idx - k * Nn;
  const float v = transposed ? W[(size_t)n * K + k] : W[(size_t)k * Nn + n];
  unsigned int u = __float_as_uint(v);
  u = u + 0x7FFFu + ((u >> 16) & 1u);
  P[(((size_t)(k >> 3)) * Nn + n) * 8 + (k & 7)] = (unsigned short)(u >> 16);
}

// ---------------------------------------------------------------------------
// LDS-free bf16 MFMA GEMM: C[M,N] = A_f32[M,K] @ Bp + bias (+relu).
// Bp is bf16 k-panel layout. Block = 4 waves (2x2), each wave a 64x64 tile,
// 4x4 mfma_f32_16x16x32_bf16 frags, fp32 accumulate. No LDS, no barriers.
// A frags: lane reads A[m+ (l&15)][k0+(l>>4)*8 + 0..7] (two float4s -> cvt).
// B frags: one 16B load from the panel (lanes 0-15 contiguous 256B).
// M%128==0, N%128==0, K%32==0 required (true for all node GEMMs).
// ---------------------------------------------------------------------------
template <bool RELU>
__global__ __launch_bounds__(256, 3) void mgemm_kernel(
    const float* __restrict__ A, const unsigned short* __restrict__ Bp,
    const float* __restrict__ bias, float* __restrict__ Cmat,
    int M, int Nn, int K)
{
  const int tid = threadIdx.x;
  const int lane = tid & 63;
  const int w = tid >> 6;
  const int m_base = blockIdx.y * 128 + (w >> 1) * 64;
  const int n_base = blockIdx.x * 128 + (w & 1) * 64;
  const int lr = lane & 15;
  const int lq = lane >> 4;
  f32x4 acc[4][4];
#pragma unroll
  for (int i = 0; i < 4; ++i)
#pragma unroll
    for (int j = 0; j < 4; ++j) acc[i][j] = (f32x4){0.f, 0.f, 0.f, 0.f};

  for (int k0 = 0; k0 < K; k0 += 32) {
    const int ka = k0 + (lq << 3);
    bf16x8 af[4], bfv[4];
#pragma unroll
    for (int mt = 0; mt < 4; ++mt) {
      const float* ap = A + (size_t)(m_base + mt * 16 + lr) * K + ka;
      af[mt] = pack_bf16_8(*(const float4*)ap, *(const float4*)(ap + 4));
    }
#pragma unroll
    for (int nt = 0; nt < 4; ++nt) {
      const size_t off =
          (((size_t)(ka >> 3)) * Nn + (n_base + nt * 16 + lr)) << 3;
      union { uint4 u; bf16x8 b; } bu;
      bu.u = *(const uint4*)(Bp + off);
      bfv[nt] = bu.b;
    }
#pragma unroll
    for (int mt = 0; mt < 4; ++mt)
#pragma unroll
      for (int nt = 0; nt < 4; ++nt)
        acc[mt][nt] = __builtin_amdgcn_mfma_f32_16x16x32_bf16(
            af[mt], bfv[nt], acc[mt][nt], 0, 0, 0);
  }
#pragma unroll
  for (int nt = 0; nt < 4; ++nt) {
    const int col = n_base + nt * 16 + lr;
    const float bv = bias[col];
#pragma unroll
    for (int mt = 0; mt < 4; ++mt) {
      const int row0 = m_base + mt * 16 + (lq << 2);
#pragma unroll
      for (int r = 0; r < 4; ++r) {
        float v = acc[mt][nt][r] + bv;
        if (RELU) v = fmaxf(v, 0.f);
        Cmat[(size_t)(row0 + r) * Nn + col] = v;
      }
    }
  }
}

// ---------------------------------------------------------------------------
// fp32 tiled GEMM (kept for encoder K=771 and tiny classifier GEMMs).
// ---------------------------------------------------------------------------
template <bool BT, bool RELU>
__global__ __launch_bounds__(256, 4) void gemm_kernel(
    const float* __restrict__ A, const float* __restrict__ B,
    const float* __restrict__ bias, float* __restrict__ Cmat,
    int M, int Nn, int K)
{
  __shared__ float As[8][132];
  __shared__ float Bs[8][132];
  const int tid = threadIdx.x;
  const int bm = blockIdx.y * 128;
  const int bn = blockIdx.x * 128;
  const int tm = (tid >> 4) << 3;
  const int tn = (tid & 15) << 3;
  float acc[8][8];
#pragma unroll
  for (int i = 0; i < 8; ++i)
#pragma unroll
    for (int j = 0; j < 8; ++j) acc[i][j] = 0.f;

  const int nk = (K + 7) >> 3;
  const bool k4 = (K & 3) == 0;
  for (int kc = 0; kc < nk; ++kc) {
    const int k0 = kc << 3;
    {
      const int r = tid >> 1;
      const int kk = (tid & 1) << 2;
      const int gm = bm + r;
      float va[4] = {0.f, 0.f, 0.f, 0.f};
      if (gm < M) {
        const size_t base = (size_t)gm * K + k0 + kk;
        if (k4 && (k0 + kk + 4 <= K)) {
          const float4 v = *(const float4*)(A + base);
          va[0] = v.x; va[1] = v.y; va[2] = v.z; va[3] = v.w;
        } else {
#pragma unroll
          for (int j = 0; j < 4; ++j)
            if (k0 + kk + j < K) va[j] = A[base + j];
        }
      }
      As[kk + 0][r] = va[0]; As[kk + 1][r] = va[1];
      As[kk + 2][r] = va[2]; As[kk + 3][r] = va[3];
    }
    if (!BT) {
      const int r = tid >> 5;
      const int cb = (tid & 31) << 2;
      float4 v = make_float4(0.f, 0.f, 0.f, 0.f);
      if (k0 + r < K) v = *(const float4*)(B + (size_t)(k0 + r) * Nn + bn + cb);
      *(float4*)&Bs[r][cb] = v;
    } else {
      const int r = tid >> 1;
      const int kk = (tid & 1) << 2;
      float vb[4] = {0.f, 0.f, 0.f, 0.f};
      if (bn + r < Nn) {
        const size_t base = (size_t)(bn + r) * K + k0 + kk;
        if (k4 && (k0 + kk + 4 <= K)) {
          const float4 v = *(const float4*)(B + base);
          vb[0] = v.x; vb[1] = v.y; vb[2] = v.z; vb[3] = v.w;
        } else {
#pragma unroll
          for (int j = 0; j < 4; ++j)
            if (k0 + kk + j < K) vb[j] = B[base + j];
        }
      }
      Bs[kk + 0][r] = vb[0]; Bs[kk + 1][r] = vb[1];
      Bs[kk + 2][r] = vb[2]; Bs[kk + 3][r] = vb[3];
    }
    __syncthreads();
#pragma unroll
    for (int k = 0; k < 8; ++k) {
      const float4 a0 = *(const float4*)&As[k][tm];
      const float4 a1 = *(const float4*)&As[k][tm + 4];
      const float4 b0 = *(const float4*)&Bs[k][tn];
      const float4 b1 = *(const float4*)&Bs[k][tn + 4];
      const float av[8] = {a0.x, a0.y, a0.z, a0.w, a1.x, a1.y, a1.z, a1.w};
      const float bv[8] = {b0.x, b0.y, b0.z, b0.w, b1.x, b1.y, b1.z, b1.w};
#pragma unroll
      for (int i = 0; i < 8; ++i)
#pragma unroll
        for (int j = 0; j < 8; ++j)
          acc[i][j] = fmaf(av[i], bv[j], acc[i][j]);
    }
    __syncthreads();
  }
#pragma unroll
  for (int i = 0; i < 8; ++i) {
    const int gm = bm + tm + i;
    if (gm >= M) continue;
    float* crow = Cmat + (size_t)gm * Nn + bn + tn;
#pragma unroll
    for (int j = 0; j < 8; ++j) {
      const int gn = bn + tn + j;
      if (gn >= Nn) continue;
      float v = acc[i][j] + (bias ? bias[gn] : 0.f);
      if (RELU) v = fmaxf(v, 0.f);
      crow[j] = v;
    }
  }
}

// ---------------------------------------------------------------------------
// CSR build: histogram of dst -> exclusive scan -> scatter edge ids.
// ---------------------------------------------------------------------------
__global__ __launch_bounds__(256) void hist_kernel(
    const int* __restrict__ dst, int* __restrict__ deg)
{
  const int e = blockIdx.x * 256 + threadIdx.x;
  atomicAdd(&deg[dst[e]], 1);
}

__global__ __launch_bounds__(256) void scan_kernel(
    const int* __restrict__ deg, int* __restrict__ row_ptr,
    int* __restrict__ fill)
{
  __shared__ int part[256];
  const int t = threadIdx.x;
  const int base = t << 8;
  int s = 0;
  for (int j = 0; j < 256; ++j) s += deg[base + j];
  part[t] = s;
  __syncthreads();
  for (int off = 1; off < 256; off <<= 1) {
    int v = (t >= off) ? part[t - off] : 0;
    __syncthreads();
    part[t] += v;
    __syncthreads();
  }
  int run = (t == 0) ? 0 : part[t - 1];
  for (int j = 0; j < 256; ++j) {
    row_ptr[base + j] = run;
    fill[base + j] = run;
    run += deg[base + j];
  }
  if (t == 255) row_ptr[65536] = run;
}

__global__ __launch_bounds__(256) void scatter_kernel(
    const int* __restrict__ dst, int* __restrict__ fill,
    int* __restrict__ eid)
{
  const int e = blockIdx.x * 256 + threadIdx.x;
  const int pos = atomicAdd(&fill[dst[e]], 1);
  eid[pos] = e;
}

// ---------------------------------------------------------------------------
// CSR-ordered fused GINE kernel (unchanged from round 4; every acc[] loop
// FULLY unrolled — partial unroll demotes acc to scratch).
// ---------------------------------------------------------------------------
__global__ __launch_bounds__(256, 3) void gine2_kernel(
    const float* __restrict__ edge_attr,
    const int* __restrict__ src_idx, const int* __restrict__ dst_idx,
    const int* __restrict__ row_ptr, const int* __restrict__ eid_sorted,
    const float* __restrict__ ee_w, const float* __restrict__ ee_b,
    const float* __restrict__ elin_w, const float* __restrict__ elin_b,
    const float* __restrict__ h, const float* __restrict__ eps, int layer,
    float* __restrict__ g1)
{
  __shared__ float ea_s[64][5];
  __shared__ int si_s[64];
  __shared__ int sl_s[64];
  __shared__ float EsT[128][64];
  __shared__ float g_acc[16][256];
  const int tid = threadIdx.x;
  const int n0 = blockIdx.x << 4;
#pragma unroll
  for (int i = 0; i < 4; ++i)
    ((float4*)g_acc)[(i << 8) + tid] = make_float4(0.f, 0.f, 0.f, 0.f);
  const int row_start = row_ptr[n0];
  const int row_end = row_ptr[n0 + 16];
  const int cg = (tid & 63) << 2;
  const int eg = (tid >> 6) << 4;
  const float4 b4 = *(const float4*)(elin_b + cg);

  for (int cs = row_start; cs < row_end; cs += 64) {
    __syncthreads();
    if (tid < 64) {
      const int slot = cs + tid;
      float4 v = make_float4(0.f, 0.f, 0.f, 0.f);
      int s = 0, sl = -1;
      if (slot < row_end) {
        const int e = eid_sorted[slot];
        v = *(const float4*)(edge_attr + ((size_t)e << 2));
        s = src_idx[e];
        sl = dst_idx[e] - n0;
      }
      ea_s[tid][0] = v.x; ea_s[tid][1] = v.y;
      ea_s[tid][2] = v.z; ea_s[tid][3] = v.w;
      si_s[tid] = s; sl_s[tid] = sl;
    }
    float4 acc[16];
#pragma unroll
    for (int i = 0; i < 16; ++i) acc[i] = make_float4(0.f, 0.f, 0.f, 0.f);
    __syncthreads();

    for (int kk = 0; kk < 256; kk += 128) {
      {
        const int e = tid & 63;
        const int kb = (tid >> 6) << 5;
        const float a0 = ea_s[e][0], a1 = ea_s[e][1];
        const float a2 = ea_s[e][2], a3 = ea_s[e][3];
#pragma unroll 4
        for (int dk = 0; dk < 32; ++dk) {
          const int kl = kb + dk;
          const int gk = kk + kl;
          float v = ee_b[gk];
          v = fmaf(a0, ee_w[gk], v);
          v = fmaf(a1, ee_w[256 + gk], v);
          v = fmaf(a2, ee_w[512 + gk], v);
          v = fmaf(a3, ee_w[768 + gk], v);
          EsT[kl][e] = fmaxf(v, 0.f);
        }
      }
      __syncthreads();
#pragma unroll 2
      for (int k = 0; k < 128; ++k) {
        const float4 w4 = *(const float4*)(elin_w + (size_t)((kk + k) << 8) + cg);
#pragma unroll
        for (int q = 0; q < 4; ++q) {
          const float4 ev = *(const float4*)&EsT[k][eg + (q << 2)];
          FMA4(acc[(q << 2) + 0], ev.x, w4);
          FMA4(acc[(q << 2) + 1], ev.y, w4);
          FMA4(acc[(q << 2) + 2], ev.z, w4);
          FMA4(acc[(q << 2) + 3], ev.w, w4);
        }
      }
      __syncthreads();
    }

#pragma unroll
    for (int i = 0; i < 16; ++i) {
      const int li = eg + i;
      const int sl = sl_s[li];
      if (sl < 0) continue;
      const int s = si_s[li];
      const float4 hv = *(const float4*)(h + (((size_t)s) << 8) + cg);
      const float mx = fmaxf(hv.x + acc[i].x + b4.x, 0.f);
      const float my = fmaxf(hv.y + acc[i].y + b4.y, 0.f);
      const float mz = fmaxf(hv.z + acc[i].z + b4.z, 0.f);
      const float mw = fmaxf(hv.w + acc[i].w + b4.w, 0.f);
      atomicAdd(&g_acc[sl][cg + 0], mx);
      atomicAdd(&g_acc[sl][cg + 1], my);
      atomicAdd(&g_acc[sl][cg + 2], mz);
      atomicAdd(&g_acc[sl][cg + 3], mw);
    }
  }
  __syncthreads();

  const float f = 1.f + eps[layer];
  const int row = tid >> 4;
  const int c0 = (tid & 15) << 4;
  const size_t nb = (((size_t)(n0 + row)) << 8) + c0;
#pragma unroll
  for (int j = 0; j < 4; ++j) {
    const float4 hv = *(const float4*)(h + nb + (j << 2));
    const float4 av = *(const float4*)&g_acc[row][c0 + (j << 2)];
    float4 o;
    o.x = fmaf(f, hv.x, av.x);
    o.y = fmaf(f, hv.y, av.y);
    o.z = fmaf(f, hv.z, av.z);
    o.w = fmaf(f, hv.w, av.w);
    *(float4*)(g1 + nb + (j << 2)) = o;
  }
}

// ---------------------------------------------------------------------------
// Streaming attention, one block per (graph, head).
// ---------------------------------------------------------------------------
__global__ __launch_bounds__(256, 2) void attn_kernel(
    const float* __restrict__ qkv, float* __restrict__ o)
{
  __shared__ float k_s[128][64];
  __shared__ float v_s[128][64];
  const int gh = blockIdx.x;
  const int g = gh >> 2;
  const int hh = gh & 3;
  const int p = threadIdx.x;
  const float scale = 0.125f;
  const float* qrow = qkv + ((size_t)(g * 256 + p)) * 768 + hh * 64;
  float4 q[16];
#pragma unroll
  for (int i = 0; i < 16; ++i) q[i] = *(const float4*)(qrow + (i << 2));
  float4 oa[16];
#pragma unroll
  for (int i = 0; i < 16; ++i) oa[i] = make_float4(0.f, 0.f, 0.f, 0.f);
  float l = 0.f;
  for (int kb = 0; kb < 256; kb += 128) {
    __syncthreads();
#pragma unroll
    for (int it = 0; it < 8; ++it) {
      const int idx = it * 256 + p;
      const int row = idx >> 4;
      const int c4 = (idx & 15) << 2;
      const float* base = qkv + ((size_t)(g * 256 + kb + row)) * 768 + hh * 64 + c4;
      *(float4*)&k_s[row][c4] = *(const float4*)(base + 256);
      *(float4*)&v_s[row][c4] = *(const float4*)(base + 512);
    }
    __syncthreads();
    for (int j = 0; j < 128; ++j) {
      const float* kr = k_s[j];
      float s = 0.f;
#pragma unroll
      for (int i = 0; i < 16; ++i) {
        const float4 kv = *(const float4*)(kr + (i << 2));
        s = fmaf(q[i].x, kv.x, s);
        s = fmaf(q[i].y, kv.y, s);
        s = fmaf(q[i].z, kv.z, s);
        s = fmaf(q[i].w, kv.w, s);
      }
      const float pe = __expf(s * scale);
      l += pe;
      const float* vr = v_s[j];
#pragma unroll
      for (int i = 0; i < 16; ++i) {
        const float4 vv = *(const float4*)(vr + (i << 2));
        FMA4(oa[i], pe, vv);
      }
    }
  }
  const float inv = 1.f / l;
  float* orow = o + ((size_t)(g * 256 + p)) * 256 + hh * 64;
#pragma unroll
  for (int i = 0; i < 16; ++i) {
    float4 t = oa[i];
    t.x *= inv; t.y *= inv; t.z *= inv; t.w *= inv;
    *(float4*)(orow + (i << 2)) = t;
  }
}

// ---------------------------------------------------------------------------
__global__ __launch_bounds__(256) void ln_kernel(
    const float* __restrict__ a, const float* __restrict__ res,
    const float* __restrict__ gam, const float* __restrict__ bet,
    float* __restrict__ out, int relu)
{
  __shared__ float2 red[256];
  const int t = threadIdx.x;
  const size_t base = (size_t)blockIdx.x * 256;
  float v = a[base + t];
  if (res) v += res[base + t];
  red[t] = make_float2(v, v * v);
  __syncthreads();
#pragma unroll
  for (int s = 128; s > 0; s >>= 1) {
    if (t < s) { red[t].x += red[t + s].x; red[t].y += red[t + s].y; }
    __syncthreads();
  }
  const float mu = red[0].x * (1.f / 256.f);
  const float var = red[0].y * (1.f / 256.f) - mu * mu;
  float r = (v - mu) * rsqrtf(var + 1e-5f) * gam[t] + bet[t];
  if (relu) r = fmaxf(r, 0.f);
  out[base + t] = r;
}

__global__ __launch_bounds__(256) void bn_stats_kernel(
    const float* __restrict__ y, float* __restrict__ stats)
{
  const int t = threadIdx.x;
  const size_t r0 = (size_t)blockIdx.x * 64;
  float s = 0.f, s2 = 0.f;
  for (int r = 0; r < 64; ++r) {
    const float v = y[(r0 + r) * 256 + t];
    s += v;
    s2 = fmaf(v, v, s2);
  }
  atomicAdd(&stats[t], s);
  atomicAdd(&stats[256 + t], s2);
}

__global__ __launch_bounds__(256) void bn_apply_kernel(
    float* __restrict__ y, const float* __restrict__ stats,
    const float* __restrict__ gam, const float* __restrict__ bet)
{
  const size_t i = ((size_t)blockIdx.x * 256 + threadIdx.x) << 2;
  const int c = (int)(i & 255);
  const float inv_n = 1.f / 65536.f;
  float4 v = *(float4*)(y + i);
  const float4 s4 = *(const float4*)(stats + c);
  const float4 q4 = *(const float4*)(stats + 256 + c);
  const float4 g4 = *(const float4*)(gam + c);
  const float4 b4 = *(const float4*)(bet + c);
  float mu, var, sc;
  mu = s4.x * inv_n; var = q4.x * inv_n - mu * mu; sc = g4.x * rsqrtf(var + 1e-5f);
  v.x = fmaxf((v.x - mu) * sc + b4.x, 0.f);
  mu = s4.y * inv_n; var = q4.y * inv_n - mu * mu; sc = g4.y * rsqrtf(var + 1e-5f);
  v.y = fmaxf((v.y - mu) * sc + b4.y, 0.f);
  mu = s4.z * inv_n; var = q4.z * inv_n - mu * mu; sc = g4.z * rsqrtf(var + 1e-5f);
  v.z = fmaxf((v.z - mu) * sc + b4.z, 0.f);
  mu = s4.w * inv_n; var = q4.w * inv_n - mu * mu; sc = g4.w * rsqrtf(var + 1e-5f);
  v.w = fmaxf((v.w - mu) * sc + b4.w, 0.f);
  *(float4*)(y + i) = v;
}

__global__ __launch_bounds__(256) void add_kernel(
    const float* __restrict__ a, const float* __restrict__ b,
    float* __restrict__ out)
{
  const size_t i = ((size_t)blockIdx.x * 256 + threadIdx.x) << 2;
  const float4 va = *(const float4*)(a + i);
  const float4 vb = *(const float4*)(b + i);
  float4 v;
  v.x = va.x + vb.x; v.y = va.y + vb.y; v.z = va.z + vb.z; v.w = va.w + vb.w;
  *(float4*)(out + i) = v;
}

__global__ __launch_bounds__(256) void pool_kernel(
    const float* __restrict__ h, const int* __restrict__ batch,
    float* __restrict__ sums, float* __restrict__ cnt)
{
  const int t = threadIdx.x;
  const int n0 = blockIdx.x * 256;
  float acc = 0.f, runc = 0.f;
  int cur = batch[n0];
  for (int r = 0; r < 256; ++r) {
    const int n = n0 + r;
    const int b = batch[n];
    if (b != cur) {
      atomicAdd(&sums[(size_t)cur * 256 + t], acc);
      if (t == 0) atomicAdd(&cnt[cur], runc);
      acc = 0.f; runc = 0.f; cur = b;
    }
    acc += h[(size_t)n * 256 + t];
    runc += 1.f;
  }
  atomicAdd(&sums[(size_t)cur * 256 + t], acc);
  if (t == 0) atomicAdd(&cnt[cur], runc);
}

__global__ __launch_bounds__(256) void gemb_kernel(
    const float* __restrict__ sums, const float* __restrict__ cnt,
    float* __restrict__ gemb)
{
  const int i = blockIdx.x * 256 + threadIdx.x;
  const int g = i >> 8;
  gemb[i] = sums[i] / fmaxf(cnt[g], 1.f);
}

__global__ __launch_bounds__(256) void head_kernel(
    const float* __restrict__ z2, const float* __restrict__ w3,
    const float* __restrict__ b3, float* __restrict__ out)
{
  __shared__ float w[128];
  const int t = threadIdx.x;
  if (t < 128) w[t] = w3[t];
  __syncthreads();
  float s = 0.f;
  const float* row = z2 + (size_t)t * 128;
#pragma unroll 4
  for (int d = 0; d < 128; ++d) s = fmaf(row[d], w[d], s);
  out[t] = s + b3[0];
}

// ---------------------------------------------------------------------------
extern "C" void kernel_launch(void* const* d_in, const int* in_sizes, int n_in,
                              void* d_out, int out_size, void* d_ws, size_t ws_size,
                              hipStream_t stream)
{
  const float* x          = (const float*)d_in[0];
  const int*   edge_index = (const int*)d_in[1];
  const int*   batch      = (const int*)d_in[2];
  const float* edge_attr  = (const float*)d_in[3];
  const float* ne_w   = (const float*)d_in[4];
  const float* ne_b   = (const float*)d_in[5];
  const float* ne_ln_g = (const float*)d_in[6];
  const float* ne_ln_b = (const float*)d_in[7];
  const float* ee_w   = (const float*)d_in[8];
  const float* ee_b   = (const float*)d_in[9];
  const float* eps    = (const float*)d_in[10];
  const float* elin_w = (const float*)d_in[11];
  const float* gin_w1 = (const float*)d_in[12];
  const float* gin_w2 = (const float*)d_in[13];
  const float* attn_in_w  = (const float*)d_in[14];
  const float* attn_out_w = (const float*)d_in[15];
  const float* mlp_w1 = (const float*)d_in[16];
  const float* mlp_w2 = (const float*)d_in[17];
  const float* elin_b = (const float*)d_in[18];
  const float* gin_b1 = (const float*)d_in[19];
  const float* gin_b2 = (const float*)d_in[20];
  const float* attn_in_b  = (const float*)d_in[21];
  const float* attn_out_b = (const float*)d_in[22];
  const float* mlp_b1 = (const float*)d_in[23];
  const float* mlp_b2 = (const float*)d_in[24];
  const float* gin_bn_g = (const float*)d_in[25];
  const float* ln1_g  = (const float*)d_in[26];
  const float* ln2_g  = (const float*)d_in[27];
  const float* ln3_g  = (const float*)d_in[28];
  const float* gin_bn_b = (const float*)d_in[29];
  const float* ln1_b  = (const float*)d_in[30];
  const float* ln2_b  = (const float*)d_in[31];
  const float* ln3_b  = (const float*)d_in[32];
  const float* cls_w1 = (const float*)d_in[33];
  const float* cls_b1 = (const float*)d_in[34];
  const float* cls_ln_g = (const float*)d_in[35];
  const float* cls_ln_b = (const float*)d_in[36];
  const float* cls_w2 = (const float*)d_in[37];
  const float* cls_b2 = (const float*)d_in[38];
  const float* cls_w3 = (const float*)d_in[39];
  const float* cls_b3 = (const float*)d_in[40];

  const int* src = edge_index;
  const int* dst = edge_index + N_EDGES;

  float* ws = (float*)d_ws;
  const size_t NC = (size_t)N_NODES * CH;       // 16,777,216
  float* h    = ws;
  float* bufA = ws + NC;
  float* bufB = ws + 2 * NC;
  float* bufC = ws + 3 * NC;
  float* bufQ = ws + 4 * NC;                    // qkv [N,768] -> m1 [N,512]
  float* stats = bufQ + (size_t)N_NODES * 768;  // 4*512
  int* ideg  = (int*)(stats + 2048);            // 65536
  int* ifill = ideg + 65536;                    // 65536
  int* irow  = ifill + 65536;                   // 65537 (padded to 65544)
  int* ieid  = irow + 65544;                    // 524288
  unsigned short* pan = (unsigned short*)(ieid + 524288);  // 2.62M bf16 panels
  // post-loop scratch reuses bufA (dead after last layer):
  float* sums = bufA;
  float* cnt  = bufA + 65536;
  float* gemb = bufA + 65792;
  float* z1   = bufA + 131328;
  float* z2   = bufA + 196864;

  const dim3 blk(256);
  const size_t PL = 655360;  // panel elems per layer

  // ---- CSR build + weight bf16 panelization (once) ----
  hipMemsetAsync(stats, 0, 2048 * sizeof(float), stream);
  hipMemsetAsync(ideg, 0, 65536 * sizeof(int), stream);
  hist_kernel<<<dim3(2048), blk, 0, stream>>>(dst, ideg);
  scan_kernel<<<dim3(1), blk, 0, stream>>>(ideg, irow, ifill);
  scatter_kernel<<<dim3(2048), blk, 0, stream>>>(dst, ifill, ieid);
  for (int l = 0; l < 4; ++l) {
    unsigned short* p = pan + l * PL;
    wcvt_kernel<<<dim3(256), blk, 0, stream>>>(gin_w1 + (size_t)l * 65536, p, 256, 256, 0);
    wcvt_kernel<<<dim3(256), blk, 0, stream>>>(gin_w2 + (size_t)l * 65536, p + 65536, 256, 256, 0);
    wcvt_kernel<<<dim3(768), blk, 0, stream>>>(attn_in_w + (size_t)l * 196608, p + 131072, 256, 768, 1);
    wcvt_kernel<<<dim3(256), blk, 0, stream>>>(attn_out_w + (size_t)l * 65536, p + 327680, 256, 256, 1);
    wcvt_kernel<<<dim3(512), blk, 0, stream>>>(mlp_w1 + (size_t)l * 131072, p + 393216, 256, 512, 0);
    wcvt_kernel<<<dim3(512), blk, 0, stream>>>(mlp_w2 + (size_t)l * 131072, p + 524288, 512, 256, 0);
  }

  // ---- encoders (K=771: stays fp32) ----
  gemm_kernel<false, false><<<dim3(2, 512), blk, 0, stream>>>(
      x, ne_w, ne_b, bufB, N_NODES, 256, 771);
  ln_kernel<<<dim3(N_NODES), blk, 0, stream>>>(bufB, nullptr, ne_ln_g, ne_ln_b, h, 1);

  for (int l = 0; l < 4; ++l) {
    unsigned short* p = pan + l * PL;
    // ---- GINEConv ----
    gine2_kernel<<<dim3(4096), blk, 0, stream>>>(
        edge_attr, src, dst, irow, ieid, ee_w, ee_b,
        elin_w + (size_t)l * 65536, elin_b + l * 256, h, eps, l, bufA);
    mgemm_kernel<false><<<dim3(2, 512), blk, 0, stream>>>(
        bufA, p, gin_b1 + l * 256, bufB, N_NODES, 256, 256);
    bn_stats_kernel<<<dim3(1024), blk, 0, stream>>>(bufB, stats + l * 512);
    bn_apply_kernel<<<dim3(16384), blk, 0, stream>>>(
        bufB, stats + l * 512, gin_bn_g + l * 256, gin_bn_b + l * 256);
    mgemm_kernel<false><<<dim3(2, 512), blk, 0, stream>>>(
        bufB, p + 65536, gin_b2 + l * 256, bufC, N_NODES, 256, 256);
    ln_kernel<<<dim3(N_NODES), blk, 0, stream>>>(
        bufC, h, ln1_g + l * 256, ln1_b + l * 256, bufC, 0);
    // ---- attention ----
    mgemm_kernel<false><<<dim3(6, 512), blk, 0, stream>>>(
        h, p + 131072, attn_in_b + l * 768, bufQ, N_NODES, 768, 256);
    attn_kernel<<<dim3(1024), blk, 0, stream>>>(bufQ, bufA);
    mgemm_kernel<false><<<dim3(2, 512), blk, 0, stream>>>(
        bufA, p + 327680, attn_out_b + l * 256, bufB, N_NODES, 256, 256);
    ln_kernel<<<dim3(N_NODES), blk, 0, stream>>>(
        bufB, h, ln2_g + l * 256, ln2_b + l * 256, bufB, 0);
    // ---- FFN ----
    add_kernel<<<dim3(16384), blk, 0, stream>>>(bufC, bufB, bufB);
    mgemm_kernel<true><<<dim3(4, 512), blk, 0, stream>>>(
        bufB, p + 393216, mlp_b1 + l * 512, bufQ, N_NODES, 512, 256);
    mgemm_kernel<false><<<dim3(2, 512), blk, 0, stream>>>(
        bufQ, p + 524288, mlp_b2 + l * 256, bufC, N_NODES, 256, 512);
    ln_kernel<<<dim3(N_NODES), blk, 0, stream>>>(
        bufC, bufB, ln3_g + l * 256, ln3_b + l * 256, h, 0);
  }

  // ---- pooling + classifier ----
  hipMemsetAsync(sums, 0, 65792 * sizeof(float), stream);
  pool_kernel<<<dim3(256), blk, 0, stream>>>(h, batch, sums, cnt);
  gemb_kernel<<<dim3(256), blk, 0, stream>>>(sums, cnt, gemb);
  gemm_kernel<false, false><<<dim3(2, 2), blk, 0, stream>>>(
      gemb, cls_w1, cls_b1, z1, 256, 256, 256);
  ln_kernel<<<dim3(256), blk, 0, stream>>>(z1, nullptr, cls_ln_g, cls_ln_b, z1, 1);
  gemm_kernel<false, true><<<dim3(1, 2), blk, 0, stream>>>(
      z1, cls_w2, cls_b2, z2, 256, 128, 256);
  head_kernel<<<dim3(1), blk, 0, stream>>>(z2, cls_w3, cls_b3, (float*)d_out);
}